// Round 11
// baseline (848.611 us; speedup 1.0000x reference)
//
#include <hip/hip_runtime.h>
#include <cmath>

#define NPTS 256
#define TOTPTS 32768
#define KNB 16

// ---------------- workspace layout (float-element offsets) ----------------
// YMAX region's head doubles as per-point fp64 sq norms (256 KiB) during knn.
// Current layer's INPUT h region doubles as combine partial-sums scratch
// (input h is dead once gemm has run; apply writes the OTHER h region).
static const size_t OFF_HA   = 0;
static const size_t OFF_HB   = 4194304;
static const size_t OFF_UZ   = 6291456;
static const size_t OFF_YMAX = 23068672;
static const size_t OFF_YMIN = 31457280;
static const size_t OFF_IDX  = 39845888;
static const size_t OFF_VT   = 40370176;
static const size_t OFF_SUMS = 40458240;   // byte offset 161,832,960 (8-aligned)

__device__ __forceinline__ float gelu_erf(float v) {
  return 0.5f * v * (1.0f + erff(v * 0.70710678118654752f));
}

// ---------------- prep: transpose x -> h0, build Vt, zero stats ----------------
__global__ __launch_bounds__(256) void prep_kernel(
    const float* __restrict__ x, float* __restrict__ h0,
    const float* __restrict__ W1, const float* __restrict__ W2, const float* __restrict__ W3,
    const float* __restrict__ W4, const float* __restrict__ W5,
    float* __restrict__ Vt, double* __restrict__ sums) {
  const int stride = gridDim.x * blockDim.x;
  const int tid0 = blockIdx.x * blockDim.x + threadIdx.x;
  // x: (4,6,32,256) -> h0: (128 clouds, 256 pts, 6 ch)
  for (int id = tid0; id < 196608; id += stride) {
    int ch = id % 6;
    int r  = id / 6;            // r = cloud*256 + s
    int s  = r & 255;
    int p  = (r >> 8) & 31;
    int bs = r >> 13;
    h0[id] = x[(((size_t)(bs * 6 + ch) * 32 + p) << 8) + s];
  }
  // Vt[l]: (Cin x 2O), Vt[c*2O + j] = W[j<O ? j*2Cin+c : (j-O)*2Cin+Cin+c]
  for (int id = tid0; id < 87232; id += stride) {
    const float* W; int K, N2, base;
    if (id < 192)        { W = W1; K = 6;   N2 = 32;  base = 0; }
    else if (id < 1216)  { W = W2; K = 16;  N2 = 64;  base = 192; }
    else if (id < 5312)  { W = W3; K = 32;  N2 = 128; base = 1216; }
    else if (id < 21696) { W = W4; K = 64;  N2 = 256; base = 5312; }
    else                 { W = W5; K = 128; N2 = 512; base = 21696; }
    int e = id - base;
    int c = e / N2;
    int j = e - c * N2;
    int O = N2 >> 1;
    Vt[id] = (j < O) ? W[j * 2 * K + c] : W[(j - O) * 2 * K + K + c];
  }
  for (int id = tid0; id < 992; id += stride) sums[id] = 0.0;
}

// ---------------- sq: per-point fp64 squared norm ----------------
template<int C>
__global__ __launch_bounds__(256) void sq_kernel(const float* __restrict__ h,
                                                 double* __restrict__ sqd) {
  const int n = blockIdx.x * 256 + threadIdx.x;
  const float* p = h + (size_t)n * C;
  double q0 = 0.0, q1 = 0.0;
  #pragma unroll
  for (int c = 0; c + 1 < C; c += 2) {
    q0 = fma((double)p[c],   (double)p[c],   q0);
    q1 = fma((double)p[c+1], (double)p[c+1], q1);
  }
  #pragma unroll
  for (int c = C & ~1; c < C; ++c) q0 = fma((double)p[c], (double)p[c], q0);
  sqd[n] = q0 + q1;
}

// ---------------- fused knn v3 + top-2 select ----------------
// GEMM/keys/staging identical to the 648 µs champion (v3): fp64 keys,
// conflict-free LDS, lane c owns cols {4c..4c+3} U {128+4c..128+4c+3}.
// SELECT CHANGE: each round extracts the global rank-2r AND rank-2r+1
// together. Each lane contributes its sorted local pair (head, second); the
// 5-step butterfly merges sorted pairs: first = min(p0,q0), second =
// min(max(p0,q0), min(p1,q1)). 8 rounds instead of 16 -> dependent-shfl chain
// halves. Keys are a strict total order (unique col in low bits), the global
// top-2 of the union is contained in the per-lane top-2 pairs, and owner-pop
// (1 or 2 from the sorted head) removes exactly the extracted keys -> the
// extracted SET is identical to the 16-round version -> identical indices.
template<int K>
__global__ __launch_bounds__(256) void knn_fused_kernel(const float* __restrict__ h,
                                                        const double* __restrict__ sqd,
                                                        int* __restrict__ idxout) {
  constexpr int KC  = (K < 16) ? K : 16;
  constexpr int AST = 18;                       // As stride (even -> float2 align)
  constexpr int BST = 260;                      // Bs stride (%4==0 -> float4 align)
  __shared__ __align__(16) float As[KC * AST];  // [k][i], i in 0..15
  __shared__ __align__(16) float Bs[KC * BST];  // [k][j], j in 0..255
  const int xcd   = blockIdx.x & 7;
  const int q     = blockIdx.x >> 3;            // 0..255
  const int cloud = xcd + 8 * (q >> 4);         // 16 clouds per xcd
  const int strip = q & 15;
  const int i0    = strip * 16;
  const float* hb = h + (size_t)cloud * NPTS * K;
  const int tid = threadIdx.x;
  const int c   = tid & 31;                     // col-group owner id
  const int g   = tid >> 5;                     // row-pair: rows 2g, 2g+1

  double acc[2][8];
  #pragma unroll
  for (int r = 0; r < 2; ++r)
    #pragma unroll
    for (int j = 0; j < 8; ++j) acc[r][j] = 0.0;

  for (int k0 = 0; k0 < K; k0 += KC) {
    if (K >= 16) {
      // A: 16 rows x 16 k = 256 elems, 1/thread; 64B-coalesced per row.
      {
        int am = tid >> 4, ac = tid & 15;
        As[ac * AST + am] = hb[(size_t)(i0 + am) * K + k0 + ac];
      }
      // B: 256 rows x 16 k via float4 global reads; LDS writes 2-lanes/bank.
      #pragma unroll
      for (int qq = 0; qq < 4; ++qq) {
        int idx = tid + 256 * qq;
        int j  = idx >> 2;                      // 0..255
        int kq = idx & 3;                       // float4 slot in k
        float4 v = *(const float4*)(hb + (size_t)j * K + k0 + 4 * kq);
        Bs[(4 * kq + 0) * BST + j] = v.x;
        Bs[(4 * kq + 1) * BST + j] = v.y;
        Bs[(4 * kq + 2) * BST + j] = v.z;
        Bs[(4 * kq + 3) * BST + j] = v.w;
      }
    } else {
      // K=6 scalar staging (KC=K, single iteration)
      for (int e = tid; e < 16 * KC; e += 256) {
        int am = e / KC, ac = e - am * KC;
        As[ac * AST + am] = hb[(size_t)(i0 + am) * K + ac];
      }
      for (int e = tid; e < 256 * KC; e += 256) {
        int bm = e / KC, bc = e - bm * KC;
        Bs[bc * BST + bm] = hb[(size_t)bm * K + bc];
      }
    }
    __syncthreads();
    #pragma unroll
    for (int kk = 0; kk < KC; ++kk) {
      float2 af  = *(const float2*)(As + kk * AST + 2 * g);
      float4 bf0 = *(const float4*)(Bs + kk * BST + 4 * c);         // cols 4c..4c+3
      float4 bf1 = *(const float4*)(Bs + kk * BST + 128 + 4 * c);   // cols 128+4c..
      double a0 = (double)af.x, a1 = (double)af.y;
      double b0 = (double)bf0.x, b1 = (double)bf0.y, b2 = (double)bf0.z, b3 = (double)bf0.w;
      double b4 = (double)bf1.x, b5 = (double)bf1.y, b6 = (double)bf1.z, b7 = (double)bf1.w;
      acc[0][0] = fma(a0, b0, acc[0][0]);
      acc[0][1] = fma(a0, b1, acc[0][1]);
      acc[0][2] = fma(a0, b2, acc[0][2]);
      acc[0][3] = fma(a0, b3, acc[0][3]);
      acc[0][4] = fma(a0, b4, acc[0][4]);
      acc[0][5] = fma(a0, b5, acc[0][5]);
      acc[0][6] = fma(a0, b6, acc[0][6]);
      acc[0][7] = fma(a0, b7, acc[0][7]);
      acc[1][0] = fma(a1, b0, acc[1][0]);
      acc[1][1] = fma(a1, b1, acc[1][1]);
      acc[1][2] = fma(a1, b2, acc[1][2]);
      acc[1][3] = fma(a1, b3, acc[1][3]);
      acc[1][4] = fma(a1, b4, acc[1][4]);
      acc[1][5] = fma(a1, b5, acc[1][5]);
      acc[1][6] = fma(a1, b6, acc[1][6]);
      acc[1][7] = fma(a1, b7, acc[1][7]);
    }
    __syncthreads();
  }

  // ---- key build (same v arithmetic; col = absolute column id) ----
  const double sqi0 = sqd[cloud * NPTS + i0 + 2 * g];
  const double sqi1 = sqd[cloud * NPTS + i0 + 2 * g + 1];
  double sqj[8];
  #pragma unroll
  for (int e = 0; e < 4; ++e) {
    sqj[e]     = sqd[cloud * NPTS + 4 * c + e];
    sqj[4 + e] = sqd[cloud * NPTS + 128 + 4 * c + e];
  }
  const unsigned cb0 = 4u * (unsigned)c;
  const unsigned cb1 = 128u + 4u * (unsigned)c;

  #define MK(P, COLV) ((((unsigned long long)__double_as_longlong(P)) & ~0xFFull) | (COLV))
  unsigned long long a0 = MK(2.0 * acc[0][0] - sqi0 - sqj[0], cb0 + 0u);
  unsigned long long a1 = MK(2.0 * acc[0][1] - sqi0 - sqj[1], cb0 + 1u);
  unsigned long long a2 = MK(2.0 * acc[0][2] - sqi0 - sqj[2], cb0 + 2u);
  unsigned long long a3 = MK(2.0 * acc[0][3] - sqi0 - sqj[3], cb0 + 3u);
  unsigned long long a4 = MK(2.0 * acc[0][4] - sqi0 - sqj[4], cb1 + 0u);
  unsigned long long a5 = MK(2.0 * acc[0][5] - sqi0 - sqj[5], cb1 + 1u);
  unsigned long long a6 = MK(2.0 * acc[0][6] - sqi0 - sqj[6], cb1 + 2u);
  unsigned long long a7 = MK(2.0 * acc[0][7] - sqi0 - sqj[7], cb1 + 3u);
  unsigned long long b0 = MK(2.0 * acc[1][0] - sqi1 - sqj[0], cb0 + 0u);
  unsigned long long b1 = MK(2.0 * acc[1][1] - sqi1 - sqj[1], cb0 + 1u);
  unsigned long long b2 = MK(2.0 * acc[1][2] - sqi1 - sqj[2], cb0 + 2u);
  unsigned long long b3 = MK(2.0 * acc[1][3] - sqi1 - sqj[3], cb0 + 3u);
  unsigned long long b4 = MK(2.0 * acc[1][4] - sqi1 - sqj[4], cb1 + 0u);
  unsigned long long b5 = MK(2.0 * acc[1][5] - sqi1 - sqj[5], cb1 + 1u);
  unsigned long long b6 = MK(2.0 * acc[1][6] - sqi1 - sqj[6], cb1 + 2u);
  unsigned long long b7 = MK(2.0 * acc[1][7] - sqi1 - sqj[7], cb1 + 3u);
  #undef MK

  // Batcher odd-even sort-8, ascending (19 CE), on named scalars
  #define CE(X, Y) { unsigned long long lo_ = (X < Y) ? X : Y; \
                     unsigned long long hi_ = (X < Y) ? Y : X; X = lo_; Y = hi_; }
  #define SORT8(v0,v1,v2,v3,v4,v5,v6,v7) \
    CE(v0,v1) CE(v2,v3) CE(v4,v5) CE(v6,v7) \
    CE(v0,v2) CE(v1,v3) CE(v4,v6) CE(v5,v7) \
    CE(v1,v2) CE(v5,v6) \
    CE(v0,v4) CE(v1,v5) CE(v2,v6) CE(v3,v7) \
    CE(v2,v4) CE(v3,v5) \
    CE(v1,v2) CE(v3,v4) CE(v5,v6)
  SORT8(a0,a1,a2,a3,a4,a5,a6,a7)
  SORT8(b0,b1,b2,b3,b4,b5,b6,b7)
  #undef SORT8
  #undef CE

  // ---- select: distributed merge, TOP-2 per round (8 rounds) ----
  // Round r extracts global ranks 2r (-> lane 2r) and 2r+1 (-> lane 2r+1).
  const unsigned long long FULL = 0xFFFFFFFFFFFFFFFFull;
  const int sub = c;
  int keep1 = 0, keep2 = 0;
  for (int round = 0; round < 8; ++round) {
    // sorted local pair per chain: (list head, second)
    unsigned long long p0 = a0, p1 = a1;   // chain 1
    unsigned long long r0 = b0, r1 = b1;   // chain 2
    #define STEP2(M)                                                    \
    {                                                                   \
      unsigned long long q0_ = __shfl_xor(p0, M), q1_ = __shfl_xor(p1, M); \
      unsigned long long s0_ = __shfl_xor(r0, M), s1_ = __shfl_xor(r1, M); \
      unsigned long long hi1 = (p0 < q0_) ? q0_ : p0;                   \
      p0 = (p0 < q0_) ? p0 : q0_;                                       \
      unsigned long long mn1 = (p1 < q1_) ? p1 : q1_;                   \
      p1 = (hi1 < mn1) ? hi1 : mn1;                                     \
      unsigned long long hi2 = (r0 < s0_) ? s0_ : r0;                   \
      r0 = (r0 < s0_) ? r0 : s0_;                                       \
      unsigned long long mn2 = (r1 < s1_) ? r1 : s1_;                   \
      r1 = (hi2 < mn2) ? hi2 : mn2;                                     \
    }
    STEP2(16) STEP2(8) STEP2(4) STEP2(2) STEP2(1)
    #undef STEP2
    const int c10 = (int)(p0 & 0xFFull), c11 = (int)(p1 & 0xFFull);
    const int c20 = (int)(r0 & 0xFFull), c21 = (int)(r1 & 0xFFull);
    const int pops1 = (((c10 >> 2) & 31) == sub ? 1 : 0) + (((c11 >> 2) & 31) == sub ? 1 : 0);
    const int pops2 = (((c20 >> 2) & 31) == sub ? 1 : 0) + (((c21 >> 2) & 31) == sub ? 1 : 0);
    if (pops1 == 2) {
      a0 = a2; a1 = a3; a2 = a4; a3 = a5; a4 = a6; a5 = a7; a6 = FULL; a7 = FULL;
    } else if (pops1 == 1) {
      a0 = a1; a1 = a2; a2 = a3; a3 = a4; a4 = a5; a5 = a6; a6 = a7; a7 = FULL;
    }
    if (pops2 == 2) {
      b0 = b2; b1 = b3; b2 = b4; b3 = b5; b4 = b6; b5 = b7; b6 = FULL; b7 = FULL;
    } else if (pops2 == 1) {
      b0 = b1; b1 = b2; b2 = b3; b3 = b4; b4 = b5; b5 = b6; b6 = b7; b7 = FULL;
    }
    if (sub == 2 * round)     { keep1 = c10; keep2 = c20; }
    if (sub == 2 * round + 1) { keep1 = c11; keep2 = c21; }
  }
  if (sub < KNB) {
    const int rowA = cloud * NPTS + i0 + 2 * g;      // chain-1 row
    idxout[(size_t)rowA * KNB + sub]       = cloud * NPTS + keep1;
    idxout[(size_t)(rowA + 1) * KNB + sub] = cloud * NPTS + keep2;
  }
}

// ---------------- GEMM (small layers): UZ(32768 x 2O) = h * Vt, 64x64 tiles ----------------
template<int K, int N2>
__global__ __launch_bounds__(256) void gemm_uz_kernel(const float* __restrict__ h,
                                                      const float* __restrict__ Vt,
                                                      float* __restrict__ UZ) {
  constexpr int KC = 32;
  constexpr int NBLK = (N2 + 63) / 64;
  __shared__ __align__(16) float As[KC * 68];   // [k][m]
  __shared__ __align__(16) float Bs[KC * 68];   // [k][j]
  const int m0 = (int)(blockIdx.x / NBLK) * 64;
  const int n0 = (int)(blockIdx.x % NBLK) * 64;
  const int tid = threadIdx.x;
  const int mm = (tid & 15) * 4;
  const int jj = (tid >> 4) * 4;
  float acc[4][4] = {{0.f}};
  for (int k0 = 0; k0 < K; k0 += KC) {
    #pragma unroll
    for (int e = tid; e < 64 * KC; e += 256) {
      int am = e / KC, ac = e - am * KC;
      float v = 0.f;
      if (k0 + ac < K) v = h[(size_t)(m0 + am) * K + k0 + ac];
      As[ac * 68 + am] = v;
    }
    #pragma unroll
    for (int e = tid; e < KC * 64; e += 256) {
      int bj = e & 63, bc = e >> 6;
      float v = 0.f;
      if (k0 + bc < K && n0 + bj < N2) v = Vt[(size_t)(k0 + bc) * N2 + n0 + bj];
      Bs[bc * 68 + bj] = v;
    }
    __syncthreads();
    #pragma unroll
    for (int c = 0; c < KC; ++c) {
      float4 av = *(const float4*)(As + c * 68 + mm);
      float4 bv = *(const float4*)(Bs + c * 68 + jj);
      acc[0][0] = fmaf(av.x, bv.x, acc[0][0]);
      acc[0][1] = fmaf(av.x, bv.y, acc[0][1]);
      acc[0][2] = fmaf(av.x, bv.z, acc[0][2]);
      acc[0][3] = fmaf(av.x, bv.w, acc[0][3]);
      acc[1][0] = fmaf(av.y, bv.x, acc[1][0]);
      acc[1][1] = fmaf(av.y, bv.y, acc[1][1]);
      acc[1][2] = fmaf(av.y, bv.z, acc[1][2]);
      acc[1][3] = fmaf(av.y, bv.w, acc[1][3]);
      acc[2][0] = fmaf(av.z, bv.x, acc[2][0]);
      acc[2][1] = fmaf(av.z, bv.y, acc[2][1]);
      acc[2][2] = fmaf(av.z, bv.z, acc[2][2]);
      acc[2][3] = fmaf(av.z, bv.w, acc[2][3]);
      acc[3][0] = fmaf(av.w, bv.x, acc[3][0]);
      acc[3][1] = fmaf(av.w, bv.y, acc[3][1]);
      acc[3][2] = fmaf(av.w, bv.z, acc[3][2]);
      acc[3][3] = fmaf(av.w, bv.w, acc[3][3]);
    }
    __syncthreads();
  }
  if (n0 + jj < N2) {
    #pragma unroll
    for (int i = 0; i < 4; ++i) {
      float4 v = make_float4(acc[i][0], acc[i][1], acc[i][2], acc[i][3]);
      *(float4*)(UZ + (size_t)(m0 + mm + i) * N2 + n0 + jj) = v;
    }
  }
}

// ---------------- GEMM (big layers): 128x128 block tile, 8x8 micro-tile ----------------
template<int K, int N2>
__global__ __launch_bounds__(256) void gemm_big_kernel(const float* __restrict__ h,
                                                       const float* __restrict__ Vt,
                                                       float* __restrict__ UZ) {
  constexpr int KC = 32;
  constexpr int PAD = 132;                       // %4==0 for b128 alignment
  constexpr int NBLK = N2 / 128;
  __shared__ __align__(16) float As[KC * PAD];   // [k][m], m in 0..127
  __shared__ __align__(16) float Bs[KC * PAD];   // [k][n], n in 0..127
  const int m0 = (int)(blockIdx.x / NBLK) * 128;
  const int n0 = (int)(blockIdx.x % NBLK) * 128;
  const int tid = threadIdx.x;
  const int ra = (tid & 15) * 4;                 // A rows: ra..ra+3, 64+ra..64+ra+3
  const int ca = (tid >> 4) * 4;                 // B cols: ca..ca+3, 64+ca..64+ca+3
  float acc[8][8];
  #pragma unroll
  for (int i = 0; i < 8; ++i)
    #pragma unroll
    for (int j = 0; j < 8; ++j) acc[i][j] = 0.f;

  for (int k0 = 0; k0 < K; k0 += KC) {
    #pragma unroll
    for (int q = 0; q < 4; ++q) {
      int idx = tid + 256 * q;
      int am = idx >> 3;                         // 0..127
      int aq = idx & 7;                          // float4 slot within the 32-wide k row
      float4 v = *(const float4*)(h + (size_t)(m0 + am) * K + k0 + 4 * aq);
      As[(4 * aq + 0) * PAD + am] = v.x;
      As[(4 * aq + 1) * PAD + am] = v.y;
      As[(4 * aq + 2) * PAD + am] = v.z;
      As[(4 * aq + 3) * PAD + am] = v.w;
    }
    #pragma unroll
    for (int q = 0; q < 4; ++q) {
      int idx = tid + 256 * q;
      int bk = idx >> 5;                         // 0..31
      int bq = idx & 31;                         // float4 slot in n
      *(float4*)(Bs + bk * PAD + 4 * bq) =
          *(const float4*)(Vt + (size_t)(k0 + bk) * N2 + n0 + 4 * bq);
    }
    __syncthreads();
    #pragma unroll
    for (int cc = 0; cc < KC; ++cc) {
      float4 a0 = *(const float4*)(As + cc * PAD + ra);
      float4 a1 = *(const float4*)(As + cc * PAD + 64 + ra);
      float4 b0 = *(const float4*)(Bs + cc * PAD + ca);
      float4 b1 = *(const float4*)(Bs + cc * PAD + 64 + ca);
      float av[8] = {a0.x, a0.y, a0.z, a0.w, a1.x, a1.y, a1.z, a1.w};
      float bv[8] = {b0.x, b0.y, b0.z, b0.w, b1.x, b1.y, b1.z, b1.w};
      #pragma unroll
      for (int i = 0; i < 8; ++i)
        #pragma unroll
        for (int j = 0; j < 8; ++j)
          acc[i][j] = fmaf(av[i], bv[j], acc[i][j]);
    }
    __syncthreads();
  }
  #pragma unroll
  for (int i = 0; i < 8; ++i) {
    int row = m0 + ((i < 4) ? (ra + i) : (64 + ra + (i - 4)));
    float4 v0 = make_float4(acc[i][0], acc[i][1], acc[i][2], acc[i][3]);
    float4 v1 = make_float4(acc[i][4], acc[i][5], acc[i][6], acc[i][7]);
    *(float4*)(UZ + (size_t)row * N2 + n0 + ca) = v0;
    *(float4*)(UZ + (size_t)row * N2 + n0 + 64 + ca) = v1;
  }
}

// ------- combine: gather u rows as float4, max/min + block-partial stats ------
template<int O, int GRID>
__global__ __launch_bounds__(256) void combine_kernel(const float* __restrict__ UZ,
    const int* __restrict__ idx, const float* __restrict__ bias,
    float* __restrict__ ymax, float* __restrict__ ymin, double* __restrict__ partials) {
  constexpr int TPP = O / 4;            // threads per point
  constexpr int PPI = 256 / TPP;        // points per iteration
  constexpr int PPB = TOTPTS / GRID;    // points per block
  constexpr int ITERS = PPB / PPI;
  static_assert(ITERS >= 1, "grid too large for this O");
  constexpr int BPC = GRID / 128;       // blocks per cloud
  __shared__ double red[256];
  const int tid = threadIdx.x;
  const int oc  = tid % TPP;            // float4-channel index
  const int sub = tid / TPP;
  const int x    = blockIdx.x & 7;
  const int slot = blockIdx.x >> 3;
  const int c    = x + 8 * (slot / BPC);
  const int w    = slot % BPC;
  const int base = c * NPTS + w * PPB;
  const float4* UZ4 = (const float4*)UZ;
  float4* ymx4 = (float4*)ymax;
  float4* ymn4 = (float4*)ymin;
  const float4 b4 = ((const float4*)bias)[oc];
  double a1x = 0.0, a1y = 0.0, a1z = 0.0, a1w = 0.0;
  double a2x = 0.0, a2y = 0.0, a2z = 0.0, a2w = 0.0;
  for (int it = 0; it < ITERS; ++it) {
    int n = base + it * PPI + sub;
    const int* ip = idx + (size_t)n * KNB;
    float4 un = UZ4[(size_t)n * (O / 2) + oc];
    float4 zn = UZ4[(size_t)n * (O / 2) + O / 4 + oc];
    float4 w4 = make_float4(zn.x - un.x + b4.x, zn.y - un.y + b4.y,
                            zn.z - un.z + b4.z, zn.w - un.w + b4.w);
    float4 mx = make_float4(-INFINITY, -INFINITY, -INFINITY, -INFINITY);
    float4 mn = make_float4(INFINITY, INFINITY, INFINITY, INFINITY);
    float4 s1 = make_float4(0.f, 0.f, 0.f, 0.f);
    float4 s2 = make_float4(0.f, 0.f, 0.f, 0.f);
    #pragma unroll
    for (int kk = 0; kk < KNB; ++kk) {
      int j = ip[kk];
      float4 uv = UZ4[(size_t)j * (O / 2) + oc];
      mx.x = fmaxf(mx.x, uv.x); mx.y = fmaxf(mx.y, uv.y);
      mx.z = fmaxf(mx.z, uv.z); mx.w = fmaxf(mx.w, uv.w);
      mn.x = fminf(mn.x, uv.x); mn.y = fminf(mn.y, uv.y);
      mn.z = fminf(mn.z, uv.z); mn.w = fminf(mn.w, uv.w);
      s1.x += uv.x; s1.y += uv.y; s1.z += uv.z; s1.w += uv.w;
      s2.x = fmaf(uv.x, uv.x, s2.x); s2.y = fmaf(uv.y, uv.y, s2.y);
      s2.z = fmaf(uv.z, uv.z, s2.z); s2.w = fmaf(uv.w, uv.w, s2.w);
    }
    ymx4[(size_t)n * (O / 4) + oc] = make_float4(mx.x + w4.x, mx.y + w4.y, mx.z + w4.z, mx.w + w4.w);
    ymn4[(size_t)n * (O / 4) + oc] = make_float4(mn.x + w4.x, mn.y + w4.y, mn.z + w4.z, mn.w + w4.w);
    a1x += (double)(s1.x + 16.f * w4.x);
    a1y += (double)(s1.y + 16.f * w4.y);
    a1z += (double)(s1.z + 16.f * w4.z);
    a1w += (double)(s1.w + 16.f * w4.w);
    a2x += (double)(s2.x + 2.f * w4.x * s1.x + 16.f * (w4.x * w4.x));
    a2y += (double)(s2.y + 2.f * w4.y * s1.y + 16.f * (w4.y * w4.y));
    a2z += (double)(s2.z + 2.f * w4.z * s1.z + 16.f * (w4.z * w4.z));
    a2w += (double)(s2.w + 2.f * w4.w * s1.w + 16.f * (w4.w * w4.w));
  }
  #define REDUCE_ONE(VAL, CH_OFF)                                        \
    red[tid] = (VAL);                                                    \
    __syncthreads();                                                     \
    if (tid < TPP) {                                                     \
      double t = 0.0;                                                    \
      _Pragma("unroll")                                                  \
      for (int q = 0; q < PPI; ++q) t += red[q * TPP + tid];             \
      partials[(size_t)((CH_OFF) + 4 * tid) * GRID + blockIdx.x] = t;    \
    }                                                                    \
    __syncthreads();
  REDUCE_ONE(a1x, 0)
  REDUCE_ONE(a1y, 1)
  REDUCE_ONE(a1z, 2)
  REDUCE_ONE(a1w, 3)
  REDUCE_ONE(a2x, O + 0)
  REDUCE_ONE(a2y, O + 1)
  REDUCE_ONE(a2z, O + 2)
  REDUCE_ONE(a2w, O + 3)
  #undef REDUCE_ONE
}

// ------- reduce: per-channel sum of block partials -> sums[ch] -------
template<int NB>
__global__ __launch_bounds__(256) void reduce_sums_kernel(const double* __restrict__ part,
                                                          double* __restrict__ sums) {
  __shared__ double red[256];
  const int ch = blockIdx.x;
  const double* p = part + (size_t)ch * NB;
  double t = 0.0;
  for (int i = threadIdx.x; i < NB; i += 256) t += p[i];
  red[threadIdx.x] = t;
  __syncthreads();
  #pragma unroll
  for (int s = 128; s > 0; s >>= 1) {
    if (threadIdx.x < s) red[threadIdx.x] += red[threadIdx.x + s];
    __syncthreads();
  }
  if (threadIdx.x == 0) sums[ch] = red[0];
}

// ---------------- apply: BN affine + erf-GELU + endpoint max ----------------
template<int O>
__global__ __launch_bounds__(256) void apply_kernel(const float* __restrict__ ymax,
    const float* __restrict__ ymin, const double* __restrict__ sums,
    const float* __restrict__ g, const float* __restrict__ bt, float* __restrict__ hout) {
  const int tid = blockIdx.x * 256 + threadIdx.x;
  const int o = tid & (O - 1);
  double m = sums[o] * (1.0 / 524288.0);
  double v = fma(-m, m, sums[O + o] * (1.0 / 524288.0));
  float A = g[o] / sqrtf((float)v + 1e-5f);
  float Cc = fmaf(-(float)m, A, bt[o]);
  float r1 = gelu_erf(fmaf(A, ymax[tid], Cc));
  float r2 = gelu_erf(fmaf(A, ymin[tid], Cc));
  hout[tid] = fmaxf(r1, r2);
}

// layer-5 apply, transposes (n,o) -> (bs, o, p, s) via LDS tile
__global__ __launch_bounds__(256) void apply_final_kernel(const float* __restrict__ ymax,
    const float* __restrict__ ymin, const double* __restrict__ sums,
    const float* __restrict__ g, const float* __restrict__ bt, float* __restrict__ out) {
  constexpr int O = 256;
  __shared__ float tile[64 * 65];
  const int bo = blockIdx.x & 3;
  const int bn = blockIdx.x >> 2;
  const int n0 = bn * 64, o0 = bo * 64;
  const int lane = threadIdx.x & 63;
  const int grp = threadIdx.x >> 6;
  {
    const int oc = o0 + lane;
    double m = sums[oc] * (1.0 / 524288.0);
    double v = fma(-m, m, sums[O + oc] * (1.0 / 524288.0));
    float A = g[oc] / sqrtf((float)v + 1e-5f);
    float Cc = fmaf(-(float)m, A, bt[oc]);
    #pragma unroll
    for (int q = 0; q < 16; ++q) {
      int r = grp * 16 + q;
      size_t src = (size_t)(n0 + r) * O + oc;
      float r1 = gelu_erf(fmaf(A, ymax[src], Cc));
      float r2 = gelu_erf(fmaf(A, ymin[src], Cc));
      tile[r * 65 + lane] = fmaxf(r1, r2);
    }
  }
  __syncthreads();
  const int s0 = n0 & 255;
  const int p  = (n0 >> 8) & 31;
  const int bs = n0 >> 13;
  size_t basei = ((size_t)(bs * 256 + o0) * 32 + p) * 256 + s0;
  #pragma unroll
  for (int q = 0; q < 16; ++q) {
    int c = grp * 16 + q;
    out[basei + (size_t)c * 8192 + lane] = tile[lane * 65 + c];
  }
}

// ---------------- launch (champion schedule: serializing fork/join) ----------------
extern "C" void kernel_launch(void* const* d_in, const int* in_sizes, int n_in,
                              void* d_out, int out_size, void* d_ws, size_t ws_size,
                              hipStream_t stream) {
  (void)in_sizes; (void)n_in; (void)out_size; (void)ws_size;
  const float* x   = (const float*)d_in[0];
  const float* W1  = (const float*)d_in[1];
  const float* b1  = (const float*)d_in[2];
  const float* g1  = (const float*)d_in[3];
  const float* bt1 = (const float*)d_in[4];
  const float* W2  = (const float*)d_in[5];
  const float* b2  = (const float*)d_in[6];
  const float* g2  = (const float*)d_in[7];
  const float* bt2 = (const float*)d_in[8];
  const float* W3  = (const float*)d_in[9];
  const float* b3  = (const float*)d_in[10];
  const float* g3  = (const float*)d_in[11];
  const float* bt3 = (const float*)d_in[12];
  const float* W4  = (const float*)d_in[13];
  const float* b4  = (const float*)d_in[14];
  const float* g4  = (const float*)d_in[15];
  const float* bt4 = (const float*)d_in[16];
  const float* W5  = (const float*)d_in[17];
  const float* b5  = (const float*)d_in[18];
  const float* g5  = (const float*)d_in[19];
  const float* bt5 = (const float*)d_in[20];

  float* ws    = (float*)d_ws;
  float* hA    = ws + OFF_HA;
  float* hB    = ws + OFF_HB;
  float* UZ    = ws + OFF_UZ;
  float* ymx   = ws + OFF_YMAX;
  float* ymn   = ws + OFF_YMIN;
  int*   idxb  = (int*)(ws + OFF_IDX);
  float* Vt    = ws + OFF_VT;
  double* sums = (double*)(ws + OFF_SUMS);
  double* sqd  = (double*)ymx;   // 256 KiB scratch, free during knn phase
  double* partA = (double*)hA;   // combine partials when layer input is hA
  double* partB = (double*)hB;   // combine partials when layer input is hB

  static hipStream_t s2 = nullptr;
  static hipEvent_t evF[5], evJ[5];
  if (s2 == nullptr) {
    hipStreamCreateWithFlags(&s2, hipStreamNonBlocking);
    for (int i = 0; i < 5; ++i) {
      hipEventCreateWithFlags(&evF[i], hipEventDisableTiming);
      hipEventCreateWithFlags(&evJ[i], hipEventDisableTiming);
    }
  }

  #define FORK(l)  hipEventRecord(evF[l], stream); hipStreamWaitEvent(s2, evF[l], 0);
  #define JOIN(l)  hipEventRecord(evJ[l], s2);     hipStreamWaitEvent(stream, evJ[l], 0);

  prep_kernel<<<256, 256, 0, stream>>>(x, hA, W1, W2, W3, W4, W5, Vt, sums);

  // layer 1: hA (C=6) -> hB (O=16)
  FORK(0)
  gemm_uz_kernel<6, 32><<<512, 256, 0, s2>>>(hA, Vt + 0, UZ);
  JOIN(0)
  sq_kernel<6><<<128, 256, 0, stream>>>(hA, sqd);
  knn_fused_kernel<6><<<2048, 256, 0, stream>>>(hA, sqd, idxb);
  combine_kernel<16, 512><<<512, 256, 0, stream>>>(UZ, idxb, b1, ymx, ymn, partA);
  reduce_sums_kernel<512><<<32, 256, 0, stream>>>(partA, sums + 0);
  apply_kernel<16><<<2048, 256, 0, stream>>>(ymx, ymn, sums + 0, g1, bt1, hB);

  // layer 2: hB (C=16) -> hA (O=32)
  FORK(1)
  gemm_uz_kernel<16, 64><<<512, 256, 0, s2>>>(hB, Vt + 192, UZ);
  JOIN(1)
  sq_kernel<16><<<128, 256, 0, stream>>>(hB, sqd);
  knn_fused_kernel<16><<<2048, 256, 0, stream>>>(hB, sqd, idxb);
  combine_kernel<32, 1024><<<1024, 256, 0, stream>>>(UZ, idxb, b2, ymx, ymn, partB);
  reduce_sums_kernel<1024><<<64, 256, 0, stream>>>(partB, sums + 32);
  apply_kernel<32><<<4096, 256, 0, stream>>>(ymx, ymn, sums + 32, g2, bt2, hA);

  // layer 3: hA (C=32) -> hB (O=64)
  FORK(2)
  gemm_big_kernel<32, 128><<<256, 256, 0, s2>>>(hA, Vt + 1216, UZ);
  JOIN(2)
  sq_kernel<32><<<128, 256, 0, stream>>>(hA, sqd);
  knn_fused_kernel<32><<<2048, 256, 0, stream>>>(hA, sqd, idxb);
  combine_kernel<64, 2048><<<2048, 256, 0, stream>>>(UZ, idxb, b3, ymx, ymn, partA);
  reduce_sums_kernel<2048><<<128, 256, 0, stream>>>(partA, sums + 96);
  apply_kernel<64><<<8192, 256, 0, stream>>>(ymx, ymn, sums + 96, g3, bt3, hB);

  // layer 4: hB (C=64) -> hA (O=128)
  FORK(3)
  gemm_big_kernel<64, 256><<<512, 256, 0, s2>>>(hB, Vt + 5312, UZ);
  JOIN(3)
  sq_kernel<64><<<128, 256, 0, stream>>>(hB, sqd);
  knn_fused_kernel<64><<<2048, 256, 0, stream>>>(hB, sqd, idxb);
  combine_kernel<128, 2048><<<2048, 256, 0, stream>>>(UZ, idxb, b4, ymx, ymn, partB);
  reduce_sums_kernel<2048><<<256, 256, 0, stream>>>(partB, sums + 224);
  apply_kernel<128><<<16384, 256, 0, stream>>>(ymx, ymn, sums + 224, g4, bt4, hA);

  // layer 5: hA (C=128) -> d_out (O=256, transposed layout)
  FORK(4)
  gemm_big_kernel<128, 512><<<1024, 256, 0, s2>>>(hA, Vt + 21696, UZ);
  JOIN(4)
  sq_kernel<128><<<128, 256, 0, stream>>>(hA, sqd);
  knn_fused_kernel<128><<<2048, 256, 0, stream>>>(hA, sqd, idxb);
  combine_kernel<256, 2048><<<2048, 256, 0, stream>>>(UZ, idxb, b5, ymx, ymn, partA);
  reduce_sums_kernel<2048><<<512, 256, 0, stream>>>(partA, sums + 480);
  apply_final_kernel<<<2048, 256, 0, stream>>>(ymx, ymn, sums + 480, g5, bt5, (float*)d_out);

  #undef FORK
  #undef JOIN
}

// Round 12
// 642.062 us; speedup vs baseline: 1.3217x; 1.3217x over previous
//
#include <hip/hip_runtime.h>
#include <cmath>

#define NPTS 256
#define TOTPTS 32768
#define KNB 16

// ---------------- workspace layout (float-element offsets) ----------------
// YMAX region's head doubles as per-point fp64 sq norms (256 KiB) during knn.
// Current layer's INPUT h region doubles as combine partial-sums scratch
// (input h is dead once gemm has run; apply writes the OTHER h region).
static const size_t OFF_HA   = 0;
static const size_t OFF_HB   = 4194304;
static const size_t OFF_UZ   = 6291456;
static const size_t OFF_YMAX = 23068672;
static const size_t OFF_YMIN = 31457280;
static const size_t OFF_IDX  = 39845888;
static const size_t OFF_VT   = 40370176;
static const size_t OFF_SUMS = 40458240;   // byte offset 161,832,960 (8-aligned)

__device__ __forceinline__ float gelu_erf(float v) {
  return 0.5f * v * (1.0f + erff(v * 0.70710678118654752f));
}

// ---------------- prep: transpose x -> h0, build Vt, zero stats ----------------
__global__ __launch_bounds__(256) void prep_kernel(
    const float* __restrict__ x, float* __restrict__ h0,
    const float* __restrict__ W1, const float* __restrict__ W2, const float* __restrict__ W3,
    const float* __restrict__ W4, const float* __restrict__ W5,
    float* __restrict__ Vt, double* __restrict__ sums) {
  const int stride = gridDim.x * blockDim.x;
  const int tid0 = blockIdx.x * blockDim.x + threadIdx.x;
  // x: (4,6,32,256) -> h0: (128 clouds, 256 pts, 6 ch)
  for (int id = tid0; id < 196608; id += stride) {
    int ch = id % 6;
    int r  = id / 6;            // r = cloud*256 + s
    int s  = r & 255;
    int p  = (r >> 8) & 31;
    int bs = r >> 13;
    h0[id] = x[(((size_t)(bs * 6 + ch) * 32 + p) << 8) + s];
  }
  // Vt[l]: (Cin x 2O), Vt[c*2O + j] = W[j<O ? j*2Cin+c : (j-O)*2Cin+Cin+c]
  for (int id = tid0; id < 87232; id += stride) {
    const float* W; int K, N2, base;
    if (id < 192)        { W = W1; K = 6;   N2 = 32;  base = 0; }
    else if (id < 1216)  { W = W2; K = 16;  N2 = 64;  base = 192; }
    else if (id < 5312)  { W = W3; K = 32;  N2 = 128; base = 1216; }
    else if (id < 21696) { W = W4; K = 64;  N2 = 256; base = 5312; }
    else                 { W = W5; K = 128; N2 = 512; base = 21696; }
    int e = id - base;
    int c = e / N2;
    int j = e - c * N2;
    int O = N2 >> 1;
    Vt[id] = (j < O) ? W[j * 2 * K + c] : W[(j - O) * 2 * K + K + c];
  }
  for (int id = tid0; id < 992; id += stride) sums[id] = 0.0;
}

// ---------------- sq: per-point fp64 squared norm ----------------
template<int C>
__global__ __launch_bounds__(256) void sq_kernel(const float* __restrict__ h,
                                                 double* __restrict__ sqd) {
  const int n = blockIdx.x * 256 + threadIdx.x;
  const float* p = h + (size_t)n * C;
  double q0 = 0.0, q1 = 0.0;
  #pragma unroll
  for (int c = 0; c + 1 < C; c += 2) {
    q0 = fma((double)p[c],   (double)p[c],   q0);
    q1 = fma((double)p[c+1], (double)p[c+1], q1);
  }
  #pragma unroll
  for (int c = C & ~1; c < C; ++c) q0 = fma((double)p[c], (double)p[c], q0);
  sqd[n] = q0 + q1;
}

// ---------------- fused knn v3: register keys + conflict-free LDS ----------------
// Block = (cloud, 16-row strip) x 256 cols; 2 rows x 8 cols per thread.
// Lane c owns cols {4c..4c+3} U {128+4c..128+4c+3} (two float4 chunks at
// canonical 16B lane stride) -> B-fragment ds_read_b128s conflict-free.
// Select ownership: owner lane of col = (col>>2)&31. Keys = fp64 bits | col.
// KC=16 -> 17.8 KB LDS, 8 blocks/CU; float4 B-staging writes 2-lanes/bank.
// FMA chains ascending-k -> bitwise-identical keys -> identical indices.
// XCD swizzle: cloud = (b&7) + 8*(b>>7): one cloud's 16 blocks on one XCD.
// CHAMPION select: 16 rounds x 5-step shfl_xor min butterfly (measured best;
// top-2-per-round variant was throughput-regressive, R10).
template<int K>
__global__ __launch_bounds__(256) void knn_fused_kernel(const float* __restrict__ h,
                                                        const double* __restrict__ sqd,
                                                        int* __restrict__ idxout) {
  constexpr int KC  = (K < 16) ? K : 16;
  constexpr int AST = 18;                       // As stride (even -> float2 align)
  constexpr int BST = 260;                      // Bs stride (%4==0 -> float4 align)
  __shared__ __align__(16) float As[KC * AST];  // [k][i], i in 0..15
  __shared__ __align__(16) float Bs[KC * BST];  // [k][j], j in 0..255
  const int xcd   = blockIdx.x & 7;
  const int q     = blockIdx.x >> 3;            // 0..255
  const int cloud = xcd + 8 * (q >> 4);         // 16 clouds per xcd
  const int strip = q & 15;
  const int i0    = strip * 16;
  const float* hb = h + (size_t)cloud * NPTS * K;
  const int tid = threadIdx.x;
  const int c   = tid & 31;                     // col-group owner id
  const int g   = tid >> 5;                     // row-pair: rows 2g, 2g+1

  double acc[2][8];
  #pragma unroll
  for (int r = 0; r < 2; ++r)
    #pragma unroll
    for (int j = 0; j < 8; ++j) acc[r][j] = 0.0;

  for (int k0 = 0; k0 < K; k0 += KC) {
    if (K >= 16) {
      // A: 16 rows x 16 k = 256 elems, 1/thread; 64B-coalesced per row.
      {
        int am = tid >> 4, ac = tid & 15;
        As[ac * AST + am] = hb[(size_t)(i0 + am) * K + k0 + ac];
      }
      // B: 256 rows x 16 k via float4 global reads; LDS writes 2-lanes/bank.
      #pragma unroll
      for (int qq = 0; qq < 4; ++qq) {
        int idx = tid + 256 * qq;
        int j  = idx >> 2;                      // 0..255
        int kq = idx & 3;                       // float4 slot in k
        float4 v = *(const float4*)(hb + (size_t)j * K + k0 + 4 * kq);
        Bs[(4 * kq + 0) * BST + j] = v.x;
        Bs[(4 * kq + 1) * BST + j] = v.y;
        Bs[(4 * kq + 2) * BST + j] = v.z;
        Bs[(4 * kq + 3) * BST + j] = v.w;
      }
    } else {
      // K=6 scalar staging (KC=K, single iteration)
      for (int e = tid; e < 16 * KC; e += 256) {
        int am = e / KC, ac = e - am * KC;
        As[ac * AST + am] = hb[(size_t)(i0 + am) * K + ac];
      }
      for (int e = tid; e < 256 * KC; e += 256) {
        int bm = e / KC, bc = e - bm * KC;
        Bs[bc * BST + bm] = hb[(size_t)bm * K + bc];
      }
    }
    __syncthreads();
    #pragma unroll
    for (int kk = 0; kk < KC; ++kk) {
      float2 af  = *(const float2*)(As + kk * AST + 2 * g);
      float4 bf0 = *(const float4*)(Bs + kk * BST + 4 * c);         // cols 4c..4c+3
      float4 bf1 = *(const float4*)(Bs + kk * BST + 128 + 4 * c);   // cols 128+4c..
      double a0 = (double)af.x, a1 = (double)af.y;
      double b0 = (double)bf0.x, b1 = (double)bf0.y, b2 = (double)bf0.z, b3 = (double)bf0.w;
      double b4 = (double)bf1.x, b5 = (double)bf1.y, b6 = (double)bf1.z, b7 = (double)bf1.w;
      acc[0][0] = fma(a0, b0, acc[0][0]);
      acc[0][1] = fma(a0, b1, acc[0][1]);
      acc[0][2] = fma(a0, b2, acc[0][2]);
      acc[0][3] = fma(a0, b3, acc[0][3]);
      acc[0][4] = fma(a0, b4, acc[0][4]);
      acc[0][5] = fma(a0, b5, acc[0][5]);
      acc[0][6] = fma(a0, b6, acc[0][6]);
      acc[0][7] = fma(a0, b7, acc[0][7]);
      acc[1][0] = fma(a1, b0, acc[1][0]);
      acc[1][1] = fma(a1, b1, acc[1][1]);
      acc[1][2] = fma(a1, b2, acc[1][2]);
      acc[1][3] = fma(a1, b3, acc[1][3]);
      acc[1][4] = fma(a1, b4, acc[1][4]);
      acc[1][5] = fma(a1, b5, acc[1][5]);
      acc[1][6] = fma(a1, b6, acc[1][6]);
      acc[1][7] = fma(a1, b7, acc[1][7]);
    }
    __syncthreads();
  }

  // ---- key build (same v arithmetic; col = absolute column id) ----
  const double sqi0 = sqd[cloud * NPTS + i0 + 2 * g];
  const double sqi1 = sqd[cloud * NPTS + i0 + 2 * g + 1];
  double sqj[8];
  #pragma unroll
  for (int e = 0; e < 4; ++e) {
    sqj[e]     = sqd[cloud * NPTS + 4 * c + e];
    sqj[4 + e] = sqd[cloud * NPTS + 128 + 4 * c + e];
  }
  const unsigned cb0 = 4u * (unsigned)c;
  const unsigned cb1 = 128u + 4u * (unsigned)c;

  #define MK(P, COLV) ((((unsigned long long)__double_as_longlong(P)) & ~0xFFull) | (COLV))
  unsigned long long a0 = MK(2.0 * acc[0][0] - sqi0 - sqj[0], cb0 + 0u);
  unsigned long long a1 = MK(2.0 * acc[0][1] - sqi0 - sqj[1], cb0 + 1u);
  unsigned long long a2 = MK(2.0 * acc[0][2] - sqi0 - sqj[2], cb0 + 2u);
  unsigned long long a3 = MK(2.0 * acc[0][3] - sqi0 - sqj[3], cb0 + 3u);
  unsigned long long a4 = MK(2.0 * acc[0][4] - sqi0 - sqj[4], cb1 + 0u);
  unsigned long long a5 = MK(2.0 * acc[0][5] - sqi0 - sqj[5], cb1 + 1u);
  unsigned long long a6 = MK(2.0 * acc[0][6] - sqi0 - sqj[6], cb1 + 2u);
  unsigned long long a7 = MK(2.0 * acc[0][7] - sqi0 - sqj[7], cb1 + 3u);
  unsigned long long b0 = MK(2.0 * acc[1][0] - sqi1 - sqj[0], cb0 + 0u);
  unsigned long long b1 = MK(2.0 * acc[1][1] - sqi1 - sqj[1], cb0 + 1u);
  unsigned long long b2 = MK(2.0 * acc[1][2] - sqi1 - sqj[2], cb0 + 2u);
  unsigned long long b3 = MK(2.0 * acc[1][3] - sqi1 - sqj[3], cb0 + 3u);
  unsigned long long b4 = MK(2.0 * acc[1][4] - sqi1 - sqj[4], cb1 + 0u);
  unsigned long long b5 = MK(2.0 * acc[1][5] - sqi1 - sqj[5], cb1 + 1u);
  unsigned long long b6 = MK(2.0 * acc[1][6] - sqi1 - sqj[6], cb1 + 2u);
  unsigned long long b7 = MK(2.0 * acc[1][7] - sqi1 - sqj[7], cb1 + 3u);
  #undef MK

  // Batcher odd-even sort-8, ascending (19 CE), on named scalars
  #define CE(X, Y) { unsigned long long lo_ = (X < Y) ? X : Y; \
                     unsigned long long hi_ = (X < Y) ? Y : X; X = lo_; Y = hi_; }
  #define SORT8(v0,v1,v2,v3,v4,v5,v6,v7) \
    CE(v0,v1) CE(v2,v3) CE(v4,v5) CE(v6,v7) \
    CE(v0,v2) CE(v1,v3) CE(v4,v6) CE(v5,v7) \
    CE(v1,v2) CE(v5,v6) \
    CE(v0,v4) CE(v1,v5) CE(v2,v6) CE(v3,v7) \
    CE(v2,v4) CE(v3,v5) \
    CE(v1,v2) CE(v3,v4) CE(v5,v6)
  SORT8(a0,a1,a2,a3,a4,a5,a6,a7)
  SORT8(b0,b1,b2,b3,b4,b5,b6,b7)
  #undef SORT8
  #undef CE

  // ---- select: proven distributed merge; owner = (col>>2)&31 ----
  const unsigned long long FULL = 0xFFFFFFFFFFFFFFFFull;
  const int sub = c;
  int keep1 = 0, keep2 = 0;
  for (int round = 0; round < KNB; ++round) {
    unsigned long long m1 = a0, m2 = b0, o;
    o = __shfl_xor(m1, 16); m1 = (o < m1) ? o : m1;
    o = __shfl_xor(m2, 16); m2 = (o < m2) ? o : m2;
    o = __shfl_xor(m1, 8);  m1 = (o < m1) ? o : m1;
    o = __shfl_xor(m2, 8);  m2 = (o < m2) ? o : m2;
    o = __shfl_xor(m1, 4);  m1 = (o < m1) ? o : m1;
    o = __shfl_xor(m2, 4);  m2 = (o < m2) ? o : m2;
    o = __shfl_xor(m1, 2);  m1 = (o < m1) ? o : m1;
    o = __shfl_xor(m2, 2);  m2 = (o < m2) ? o : m2;
    o = __shfl_xor(m1, 1);  m1 = (o < m1) ? o : m1;
    o = __shfl_xor(m2, 1);  m2 = (o < m2) ? o : m2;
    const int col1 = (int)(m1 & 0xFFull);
    const int col2 = (int)(m2 & 0xFFull);
    if (((col1 >> 2) & 31) == sub) {  // owner pops sorted-list head (== winner)
      a0 = a1; a1 = a2; a2 = a3; a3 = a4; a4 = a5; a5 = a6; a6 = a7; a7 = FULL;
    }
    if (((col2 >> 2) & 31) == sub) {
      b0 = b1; b1 = b2; b2 = b3; b3 = b4; b4 = b5; b5 = b6; b6 = b7; b7 = FULL;
    }
    if (sub == round) { keep1 = col1; keep2 = col2; }
  }
  if (sub < KNB) {
    const int rowA = cloud * NPTS + i0 + 2 * g;      // chain-1 row
    idxout[(size_t)rowA * KNB + sub]       = cloud * NPTS + keep1;
    idxout[(size_t)(rowA + 1) * KNB + sub] = cloud * NPTS + keep2;
  }
}

// ---------------- GEMM (small layers): UZ(32768 x 2O) = h * Vt, 64x64 tiles ----------------
template<int K, int N2>
__global__ __launch_bounds__(256) void gemm_uz_kernel(const float* __restrict__ h,
                                                      const float* __restrict__ Vt,
                                                      float* __restrict__ UZ) {
  constexpr int KC = 32;
  constexpr int NBLK = (N2 + 63) / 64;
  __shared__ __align__(16) float As[KC * 68];   // [k][m]
  __shared__ __align__(16) float Bs[KC * 68];   // [k][j]
  const int m0 = (int)(blockIdx.x / NBLK) * 64;
  const int n0 = (int)(blockIdx.x % NBLK) * 64;
  const int tid = threadIdx.x;
  const int mm = (tid & 15) * 4;
  const int jj = (tid >> 4) * 4;
  float acc[4][4] = {{0.f}};
  for (int k0 = 0; k0 < K; k0 += KC) {
    #pragma unroll
    for (int e = tid; e < 64 * KC; e += 256) {
      int am = e / KC, ac = e - am * KC;
      float v = 0.f;
      if (k0 + ac < K) v = h[(size_t)(m0 + am) * K + k0 + ac];
      As[ac * 68 + am] = v;
    }
    #pragma unroll
    for (int e = tid; e < KC * 64; e += 256) {
      int bj = e & 63, bc = e >> 6;
      float v = 0.f;
      if (k0 + bc < K && n0 + bj < N2) v = Vt[(size_t)(k0 + bc) * N2 + n0 + bj];
      Bs[bc * 68 + bj] = v;
    }
    __syncthreads();
    #pragma unroll
    for (int c = 0; c < KC; ++c) {
      float4 av = *(const float4*)(As + c * 68 + mm);
      float4 bv = *(const float4*)(Bs + c * 68 + jj);
      acc[0][0] = fmaf(av.x, bv.x, acc[0][0]);
      acc[0][1] = fmaf(av.x, bv.y, acc[0][1]);
      acc[0][2] = fmaf(av.x, bv.z, acc[0][2]);
      acc[0][3] = fmaf(av.x, bv.w, acc[0][3]);
      acc[1][0] = fmaf(av.y, bv.x, acc[1][0]);
      acc[1][1] = fmaf(av.y, bv.y, acc[1][1]);
      acc[1][2] = fmaf(av.y, bv.z, acc[1][2]);
      acc[1][3] = fmaf(av.y, bv.w, acc[1][3]);
      acc[2][0] = fmaf(av.z, bv.x, acc[2][0]);
      acc[2][1] = fmaf(av.z, bv.y, acc[2][1]);
      acc[2][2] = fmaf(av.z, bv.z, acc[2][2]);
      acc[2][3] = fmaf(av.z, bv.w, acc[2][3]);
      acc[3][0] = fmaf(av.w, bv.x, acc[3][0]);
      acc[3][1] = fmaf(av.w, bv.y, acc[3][1]);
      acc[3][2] = fmaf(av.w, bv.z, acc[3][2]);
      acc[3][3] = fmaf(av.w, bv.w, acc[3][3]);
    }
    __syncthreads();
  }
  if (n0 + jj < N2) {
    #pragma unroll
    for (int i = 0; i < 4; ++i) {
      float4 v = make_float4(acc[i][0], acc[i][1], acc[i][2], acc[i][3]);
      *(float4*)(UZ + (size_t)(m0 + mm + i) * N2 + n0 + jj) = v;
    }
  }
}

// ---------------- GEMM (big layers): 128x128 block tile, 8x8 micro-tile ----------------
template<int K, int N2>
__global__ __launch_bounds__(256) void gemm_big_kernel(const float* __restrict__ h,
                                                       const float* __restrict__ Vt,
                                                       float* __restrict__ UZ) {
  constexpr int KC = 32;
  constexpr int PAD = 132;                       // %4==0 for b128 alignment
  constexpr int NBLK = N2 / 128;
  __shared__ __align__(16) float As[KC * PAD];   // [k][m], m in 0..127
  __shared__ __align__(16) float Bs[KC * PAD];   // [k][n], n in 0..127
  const int m0 = (int)(blockIdx.x / NBLK) * 128;
  const int n0 = (int)(blockIdx.x % NBLK) * 128;
  const int tid = threadIdx.x;
  const int ra = (tid & 15) * 4;                 // A rows: ra..ra+3, 64+ra..64+ra+3
  const int ca = (tid >> 4) * 4;                 // B cols: ca..ca+3, 64+ca..64+ca+3
  float acc[8][8];
  #pragma unroll
  for (int i = 0; i < 8; ++i)
    #pragma unroll
    for (int j = 0; j < 8; ++j) acc[i][j] = 0.f;

  for (int k0 = 0; k0 < K; k0 += KC) {
    #pragma unroll
    for (int q = 0; q < 4; ++q) {
      int idx = tid + 256 * q;
      int am = idx >> 3;                         // 0..127
      int aq = idx & 7;                          // float4 slot within the 32-wide k row
      float4 v = *(const float4*)(h + (size_t)(m0 + am) * K + k0 + 4 * aq);
      As[(4 * aq + 0) * PAD + am] = v.x;
      As[(4 * aq + 1) * PAD + am] = v.y;
      As[(4 * aq + 2) * PAD + am] = v.z;
      As[(4 * aq + 3) * PAD + am] = v.w;
    }
    #pragma unroll
    for (int q = 0; q < 4; ++q) {
      int idx = tid + 256 * q;
      int bk = idx >> 5;                         // 0..31
      int bq = idx & 31;                         // float4 slot in n
      *(float4*)(Bs + bk * PAD + 4 * bq) =
          *(const float4*)(Vt + (size_t)(k0 + bk) * N2 + n0 + 4 * bq);
    }
    __syncthreads();
    #pragma unroll
    for (int cc = 0; cc < KC; ++cc) {
      float4 a0 = *(const float4*)(As + cc * PAD + ra);
      float4 a1 = *(const float4*)(As + cc * PAD + 64 + ra);
      float4 b0 = *(const float4*)(Bs + cc * PAD + ca);
      float4 b1 = *(const float4*)(Bs + cc * PAD + 64 + ca);
      float av[8] = {a0.x, a0.y, a0.z, a0.w, a1.x, a1.y, a1.z, a1.w};
      float bv[8] = {b0.x, b0.y, b0.z, b0.w, b1.x, b1.y, b1.z, b1.w};
      #pragma unroll
      for (int i = 0; i < 8; ++i)
        #pragma unroll
        for (int j = 0; j < 8; ++j)
          acc[i][j] = fmaf(av[i], bv[j], acc[i][j]);
    }
    __syncthreads();
  }
  #pragma unroll
  for (int i = 0; i < 8; ++i) {
    int row = m0 + ((i < 4) ? (ra + i) : (64 + ra + (i - 4)));
    float4 v0 = make_float4(acc[i][0], acc[i][1], acc[i][2], acc[i][3]);
    float4 v1 = make_float4(acc[i][4], acc[i][5], acc[i][6], acc[i][7]);
    *(float4*)(UZ + (size_t)row * N2 + n0 + ca) = v0;
    *(float4*)(UZ + (size_t)row * N2 + n0 + 64 + ca) = v1;
  }
}

// ------- combine: gather u rows as float4, max/min + block-partial stats ------
template<int O, int GRID>
__global__ __launch_bounds__(256) void combine_kernel(const float* __restrict__ UZ,
    const int* __restrict__ idx, const float* __restrict__ bias,
    float* __restrict__ ymax, float* __restrict__ ymin, double* __restrict__ partials) {
  constexpr int TPP = O / 4;            // threads per point
  constexpr int PPI = 256 / TPP;        // points per iteration
  constexpr int PPB = TOTPTS / GRID;    // points per block
  constexpr int ITERS = PPB / PPI;
  static_assert(ITERS >= 1, "grid too large for this O");
  constexpr int BPC = GRID / 128;       // blocks per cloud
  __shared__ double red[256];
  const int tid = threadIdx.x;
  const int oc  = tid % TPP;            // float4-channel index
  const int sub = tid / TPP;
  const int x    = blockIdx.x & 7;
  const int slot = blockIdx.x >> 3;
  const int c    = x + 8 * (slot / BPC);
  const int w    = slot % BPC;
  const int base = c * NPTS + w * PPB;
  const float4* UZ4 = (const float4*)UZ;
  float4* ymx4 = (float4*)ymax;
  float4* ymn4 = (float4*)ymin;
  const float4 b4 = ((const float4*)bias)[oc];
  double a1x = 0.0, a1y = 0.0, a1z = 0.0, a1w = 0.0;
  double a2x = 0.0, a2y = 0.0, a2z = 0.0, a2w = 0.0;
  for (int it = 0; it < ITERS; ++it) {
    int n = base + it * PPI + sub;
    const int* ip = idx + (size_t)n * KNB;
    float4 un = UZ4[(size_t)n * (O / 2) + oc];
    float4 zn = UZ4[(size_t)n * (O / 2) + O / 4 + oc];
    float4 w4 = make_float4(zn.x - un.x + b4.x, zn.y - un.y + b4.y,
                            zn.z - un.z + b4.z, zn.w - un.w + b4.w);
    float4 mx = make_float4(-INFINITY, -INFINITY, -INFINITY, -INFINITY);
    float4 mn = make_float4(INFINITY, INFINITY, INFINITY, INFINITY);
    float4 s1 = make_float4(0.f, 0.f, 0.f, 0.f);
    float4 s2 = make_float4(0.f, 0.f, 0.f, 0.f);
    #pragma unroll
    for (int kk = 0; kk < KNB; ++kk) {
      int j = ip[kk];
      float4 uv = UZ4[(size_t)j * (O / 2) + oc];
      mx.x = fmaxf(mx.x, uv.x); mx.y = fmaxf(mx.y, uv.y);
      mx.z = fmaxf(mx.z, uv.z); mx.w = fmaxf(mx.w, uv.w);
      mn.x = fminf(mn.x, uv.x); mn.y = fminf(mn.y, uv.y);
      mn.z = fminf(mn.z, uv.z); mn.w = fminf(mn.w, uv.w);
      s1.x += uv.x; s1.y += uv.y; s1.z += uv.z; s1.w += uv.w;
      s2.x = fmaf(uv.x, uv.x, s2.x); s2.y = fmaf(uv.y, uv.y, s2.y);
      s2.z = fmaf(uv.z, uv.z, s2.z); s2.w = fmaf(uv.w, uv.w, s2.w);
    }
    ymx4[(size_t)n * (O / 4) + oc] = make_float4(mx.x + w4.x, mx.y + w4.y, mx.z + w4.z, mx.w + w4.w);
    ymn4[(size_t)n * (O / 4) + oc] = make_float4(mn.x + w4.x, mn.y + w4.y, mn.z + w4.z, mn.w + w4.w);
    a1x += (double)(s1.x + 16.f * w4.x);
    a1y += (double)(s1.y + 16.f * w4.y);
    a1z += (double)(s1.z + 16.f * w4.z);
    a1w += (double)(s1.w + 16.f * w4.w);
    a2x += (double)(s2.x + 2.f * w4.x * s1.x + 16.f * (w4.x * w4.x));
    a2y += (double)(s2.y + 2.f * w4.y * s1.y + 16.f * (w4.y * w4.y));
    a2z += (double)(s2.z + 2.f * w4.z * s1.z + 16.f * (w4.z * w4.z));
    a2w += (double)(s2.w + 2.f * w4.w * s1.w + 16.f * (w4.w * w4.w));
  }
  #define REDUCE_ONE(VAL, CH_OFF)                                        \
    red[tid] = (VAL);                                                    \
    __syncthreads();                                                     \
    if (tid < TPP) {                                                     \
      double t = 0.0;                                                    \
      _Pragma("unroll")                                                  \
      for (int q = 0; q < PPI; ++q) t += red[q * TPP + tid];             \
      partials[(size_t)((CH_OFF) + 4 * tid) * GRID + blockIdx.x] = t;    \
    }                                                                    \
    __syncthreads();
  REDUCE_ONE(a1x, 0)
  REDUCE_ONE(a1y, 1)
  REDUCE_ONE(a1z, 2)
  REDUCE_ONE(a1w, 3)
  REDUCE_ONE(a2x, O + 0)
  REDUCE_ONE(a2y, O + 1)
  REDUCE_ONE(a2z, O + 2)
  REDUCE_ONE(a2w, O + 3)
  #undef REDUCE_ONE
}

// ------- reduce: per-channel sum of block partials -> sums[ch] -------
template<int NB>
__global__ __launch_bounds__(256) void reduce_sums_kernel(const double* __restrict__ part,
                                                          double* __restrict__ sums) {
  __shared__ double red[256];
  const int ch = blockIdx.x;
  const double* p = part + (size_t)ch * NB;
  double t = 0.0;
  for (int i = threadIdx.x; i < NB; i += 256) t += p[i];
  red[threadIdx.x] = t;
  __syncthreads();
  #pragma unroll
  for (int s = 128; s > 0; s >>= 1) {
    if (threadIdx.x < s) red[threadIdx.x] += red[threadIdx.x + s];
    __syncthreads();
  }
  if (threadIdx.x == 0) sums[ch] = red[0];
}

// ---------------- apply: BN affine + erf-GELU + endpoint max ----------------
template<int O>
__global__ __launch_bounds__(256) void apply_kernel(const float* __restrict__ ymax,
    const float* __restrict__ ymin, const double* __restrict__ sums,
    const float* __restrict__ g, const float* __restrict__ bt, float* __restrict__ hout) {
  const int tid = blockIdx.x * 256 + threadIdx.x;
  const int o = tid & (O - 1);
  double m = sums[o] * (1.0 / 524288.0);
  double v = fma(-m, m, sums[O + o] * (1.0 / 524288.0));
  float A = g[o] / sqrtf((float)v + 1e-5f);
  float Cc = fmaf(-(float)m, A, bt[o]);
  float r1 = gelu_erf(fmaf(A, ymax[tid], Cc));
  float r2 = gelu_erf(fmaf(A, ymin[tid], Cc));
  hout[tid] = fmaxf(r1, r2);
}

// layer-5 apply, transposes (n,o) -> (bs, o, p, s) via LDS tile
__global__ __launch_bounds__(256) void apply_final_kernel(const float* __restrict__ ymax,
    const float* __restrict__ ymin, const double* __restrict__ sums,
    const float* __restrict__ g, const float* __restrict__ bt, float* __restrict__ out) {
  constexpr int O = 256;
  __shared__ float tile[64 * 65];
  const int bo = blockIdx.x & 3;
  const int bn = blockIdx.x >> 2;
  const int n0 = bn * 64, o0 = bo * 64;
  const int lane = threadIdx.x & 63;
  const int grp = threadIdx.x >> 6;
  {
    const int oc = o0 + lane;
    double m = sums[oc] * (1.0 / 524288.0);
    double v = fma(-m, m, sums[O + oc] * (1.0 / 524288.0));
    float A = g[oc] / sqrtf((float)v + 1e-5f);
    float Cc = fmaf(-(float)m, A, bt[oc]);
    #pragma unroll
    for (int q = 0; q < 16; ++q) {
      int r = grp * 16 + q;
      size_t src = (size_t)(n0 + r) * O + oc;
      float r1 = gelu_erf(fmaf(A, ymax[src], Cc));
      float r2 = gelu_erf(fmaf(A, ymin[src], Cc));
      tile[r * 65 + lane] = fmaxf(r1, r2);
    }
  }
  __syncthreads();
  const int s0 = n0 & 255;
  const int p  = (n0 >> 8) & 31;
  const int bs = n0 >> 13;
  size_t basei = ((size_t)(bs * 256 + o0) * 32 + p) * 256 + s0;
  #pragma unroll
  for (int q = 0; q < 16; ++q) {
    int c = grp * 16 + q;
    out[basei + (size_t)c * 8192 + lane] = tile[lane * 65 + c];
  }
}

// ---------------- launch (champion schedule: serializing fork/join) ----------------
extern "C" void kernel_launch(void* const* d_in, const int* in_sizes, int n_in,
                              void* d_out, int out_size, void* d_ws, size_t ws_size,
                              hipStream_t stream) {
  (void)in_sizes; (void)n_in; (void)out_size; (void)ws_size;
  const float* x   = (const float*)d_in[0];
  const float* W1  = (const float*)d_in[1];
  const float* b1  = (const float*)d_in[2];
  const float* g1  = (const float*)d_in[3];
  const float* bt1 = (const float*)d_in[4];
  const float* W2  = (const float*)d_in[5];
  const float* b2  = (const float*)d_in[6];
  const float* g2  = (const float*)d_in[7];
  const float* bt2 = (const float*)d_in[8];
  const float* W3  = (const float*)d_in[9];
  const float* b3  = (const float*)d_in[10];
  const float* g3  = (const float*)d_in[11];
  const float* bt3 = (const float*)d_in[12];
  const float* W4  = (const float*)d_in[13];
  const float* b4  = (const float*)d_in[14];
  const float* g4  = (const float*)d_in[15];
  const float* bt4 = (const float*)d_in[16];
  const float* W5  = (const float*)d_in[17];
  const float* b5  = (const float*)d_in[18];
  const float* g5  = (const float*)d_in[19];
  const float* bt5 = (const float*)d_in[20];

  float* ws    = (float*)d_ws;
  float* hA    = ws + OFF_HA;
  float* hB    = ws + OFF_HB;
  float* UZ    = ws + OFF_UZ;
  float* ymx   = ws + OFF_YMAX;
  float* ymn   = ws + OFF_YMIN;
  int*   idxb  = (int*)(ws + OFF_IDX);
  float* Vt    = ws + OFF_VT;
  double* sums = (double*)(ws + OFF_SUMS);
  double* sqd  = (double*)ymx;   // 256 KiB scratch, free during knn phase
  double* partA = (double*)hA;   // combine partials when layer input is hA
  double* partB = (double*)hB;   // combine partials when layer input is hB

  static hipStream_t s2 = nullptr;
  static hipEvent_t evF[5], evJ[5];
  if (s2 == nullptr) {
    hipStreamCreateWithFlags(&s2, hipStreamNonBlocking);
    for (int i = 0; i < 5; ++i) {
      hipEventCreateWithFlags(&evF[i], hipEventDisableTiming);
      hipEventCreateWithFlags(&evJ[i], hipEventDisableTiming);
    }
  }

  #define FORK(l)  hipEventRecord(evF[l], stream); hipStreamWaitEvent(s2, evF[l], 0);
  #define JOIN(l)  hipEventRecord(evJ[l], s2);     hipStreamWaitEvent(stream, evJ[l], 0);

  prep_kernel<<<256, 256, 0, stream>>>(x, hA, W1, W2, W3, W4, W5, Vt, sums);

  // layer 1: hA (C=6) -> hB (O=16)
  FORK(0)
  gemm_uz_kernel<6, 32><<<512, 256, 0, s2>>>(hA, Vt + 0, UZ);
  JOIN(0)
  sq_kernel<6><<<128, 256, 0, stream>>>(hA, sqd);
  knn_fused_kernel<6><<<2048, 256, 0, stream>>>(hA, sqd, idxb);
  combine_kernel<16, 512><<<512, 256, 0, stream>>>(UZ, idxb, b1, ymx, ymn, partA);
  reduce_sums_kernel<512><<<32, 256, 0, stream>>>(partA, sums + 0);
  apply_kernel<16><<<2048, 256, 0, stream>>>(ymx, ymn, sums + 0, g1, bt1, hB);

  // layer 2: hB (C=16) -> hA (O=32)
  FORK(1)
  gemm_uz_kernel<16, 64><<<512, 256, 0, s2>>>(hB, Vt + 192, UZ);
  JOIN(1)
  sq_kernel<16><<<128, 256, 0, stream>>>(hB, sqd);
  knn_fused_kernel<16><<<2048, 256, 0, stream>>>(hB, sqd, idxb);
  combine_kernel<32, 1024><<<1024, 256, 0, stream>>>(UZ, idxb, b2, ymx, ymn, partB);
  reduce_sums_kernel<1024><<<64, 256, 0, stream>>>(partB, sums + 32);
  apply_kernel<32><<<4096, 256, 0, stream>>>(ymx, ymn, sums + 32, g2, bt2, hA);

  // layer 3: hA (C=32) -> hB (O=64)
  FORK(2)
  gemm_big_kernel<32, 128><<<256, 256, 0, s2>>>(hA, Vt + 1216, UZ);
  JOIN(2)
  sq_kernel<32><<<128, 256, 0, stream>>>(hA, sqd);
  knn_fused_kernel<32><<<2048, 256, 0, stream>>>(hA, sqd, idxb);
  combine_kernel<64, 2048><<<2048, 256, 0, stream>>>(UZ, idxb, b3, ymx, ymn, partA);
  reduce_sums_kernel<2048><<<128, 256, 0, stream>>>(partA, sums + 96);
  apply_kernel<64><<<8192, 256, 0, stream>>>(ymx, ymn, sums + 96, g3, bt3, hB);

  // layer 4: hB (C=64) -> hA (O=128)
  FORK(3)
  gemm_big_kernel<64, 256><<<512, 256, 0, s2>>>(hB, Vt + 5312, UZ);
  JOIN(3)
  sq_kernel<64><<<128, 256, 0, stream>>>(hB, sqd);
  knn_fused_kernel<64><<<2048, 256, 0, stream>>>(hB, sqd, idxb);
  combine_kernel<128, 2048><<<2048, 256, 0, stream>>>(UZ, idxb, b4, ymx, ymn, partB);
  reduce_sums_kernel<2048><<<256, 256, 0, stream>>>(partB, sums + 224);
  apply_kernel<128><<<16384, 256, 0, stream>>>(ymx, ymn, sums + 224, g4, bt4, hA);

  // layer 5: hA (C=128) -> d_out (O=256, transposed layout)
  FORK(4)
  gemm_big_kernel<128, 512><<<1024, 256, 0, s2>>>(hA, Vt + 21696, UZ);
  JOIN(4)
  sq_kernel<128><<<128, 256, 0, stream>>>(hA, sqd);
  knn_fused_kernel<128><<<2048, 256, 0, stream>>>(hA, sqd, idxb);
  combine_kernel<256, 2048><<<2048, 256, 0, stream>>>(UZ, idxb, b5, ymx, ymn, partA);
  reduce_sums_kernel<2048><<<512, 256, 0, stream>>>(partA, sums + 480);
  apply_final_kernel<<<2048, 256, 0, stream>>>(ymx, ymn, sums + 480, g5, bt5, (float*)d_out);

  #undef FORK
  #undef JOIN
}